// Round 15
// baseline (166.676 us; speedup 1.0000x reference)
//
#include <hip/hip_runtime.h>
#include <stdint.h>

#define DI __device__ __forceinline__

typedef __attribute__((ext_vector_type(8))) __bf16 bf16x8;
typedef __attribute__((ext_vector_type(8))) unsigned short u16x8;
typedef __attribute__((ext_vector_type(4))) float f32x4;
typedef __attribute__((ext_vector_type(4))) uint32_t u32x4;
typedef unsigned short u16;

constexpr int Bb = 4, Cc = 256, Ss = 4096, HD = 64;
constexpr int ELEMS = Bb * Cc * Ss;  // 4194304

DI float bf2f(u16 h) { union { unsigned u; float f; } x; x.u = ((unsigned)h) << 16; return x.f; }
DI u16 f2bf(float f) {
  union { float f; unsigned u; } x; x.f = f;
  return (u16)((x.u + 0x7FFFu + ((x.u >> 16) & 1u)) >> 16);
}
DI uint32_t pack2bf_trunc(float a, float b) {  // low16=bf(a), high16=bf(b), truncating
  union { float f; uint32_t u; } xa, xb;
  xa.f = a; xb.f = b;
  return __builtin_amdgcn_perm(xb.u, xa.u, 0x07060302u);
}
DI bf16x8 ldfrag(const u16* p) { return __builtin_bit_cast(bf16x8, *(const u16x8*)p); }

// async global->LDS DMA, 16B per lane. LDS dest = wave-uniform base + lane*16 (linear);
// source address is per-lane (carries the swizzle).
DI void g2l16(const u16* g, u16* l) {
  __builtin_amdgcn_global_load_lds((const __attribute__((address_space(1))) uint32_t*)(const void*)g,
                                   (__attribute__((address_space(3))) uint32_t*)(void*)l, 16, 0, 0);
}

// ---------------- kernel 0: x (B,C,S) fp32 -> xt (B,S,C) bf16; + weight conversion fused ----------------
__global__ __launch_bounds__(256) void k_transpose(const float* __restrict__ x, u16* __restrict__ xt,
                                                   const float* __restrict__ wq, const float* __restrict__ wo,
                                                   u16* __restrict__ wqb, u16* __restrict__ wob) {
  __shared__ u16 T[64][72];
  const int st = blockIdx.x, ct = blockIdx.y, b = blockIdx.z;
  const int tid = threadIdx.x;
  // fused weight conversion: 1024 blocks x 256 threads == 262144 == 196608 + 65536
  {
    int flat = blockIdx.x + 64 * blockIdx.y + 256 * blockIdx.z;
    int widx = flat * 256 + tid;
    if (widx < 196608) wqb[widx] = f2bf(wq[widx]);
    else wob[widx - 196608] = f2bf(wo[widx - 196608]);
  }
#pragma unroll
  for (int e = 0; e < 2; e++) {
    int ss = tid + e * 256;
    int r = ss >> 3, seg = ss & 7;
    size_t base = ((size_t)(b * Cc + ct * 64 + r) << 12) + st * 64 + seg * 8;
    const float4* xv = (const float4*)(x + base);
    float4 v0 = xv[0], v1 = xv[1];
    u16x8 t;
    t[0] = f2bf(v0.x); t[1] = f2bf(v0.y); t[2] = f2bf(v0.z); t[3] = f2bf(v0.w);
    t[4] = f2bf(v1.x); t[5] = f2bf(v1.y); t[6] = f2bf(v1.z); t[7] = f2bf(v1.w);
    *(u16x8*)&T[r][(seg ^ ((r >> 3) & 7)) * 8] = t;
  }
  __syncthreads();
#pragma unroll
  for (int e = 0; e < 2; e++) {
    int ss = tid + e * 256;
    int sr = ss >> 3, cseg = ss & 7;
    u16x8 o;
#pragma unroll
    for (int j = 0; j < 8; j++) {
      int row = cseg * 8 + j;
      o[j] = T[row][(((sr >> 3) ^ cseg) * 8) + (sr & 7)];
    }
    *(u16x8*)(xt + ((size_t)(b * Ss + st * 64 + sr) << 8) + ct * 64 + cseg * 8) = o;
  }
}

// ---------------- kernel 1: qkv GEMM + fused output layouts ----------------
// q:[bh][s][64]*(0.125*log2e)  k:[bh][s][64]  v -> vt [bh][d][chunk*64+slot] directly.
// Staging: linear [128][32] LDS tiles, double-buffered, global_load_lds DMA with
// pre-swizzled source granule g^(row&3), ONE barrier per K-step, DMA overlapped with MFMA.
__global__ __launch_bounds__(256) void k_qkv(const u16* __restrict__ xt, const u16* __restrict__ w,
                                             const float* __restrict__ bias,
                                             u16* __restrict__ q, u16* __restrict__ kk_, u16* __restrict__ vt) {
  __shared__ union {
    u16 ab[2][2][128][32];  // [buf][A=0/B=1][row][col] linear, XOR-granule swizzled
    u16 tile[128][136];     // epilogue staging
  } sm;
  const int tid = threadIdx.x;
  const int wv = tid >> 6, lane = tid & 63;
  const int wm = wv >> 1, wn = wv & 1;
  const int lr = lane & 15, quad = lane >> 4;
  const int r0 = blockIdx.x * 128;
  const int j0 = blockIdx.y * 128;

  // DMA staging: wave wv covers rows e*64 + wv*16 .. +16 of both 128x32 tiles. Lane l writes
  // LDS granule (row = base + l>>2, g = l&3); source granule = g ^ (row&3) = (l&3)^((l>>2)&3).
  const int srow = lane >> 2;
  const int sg = ((lane & 3) ^ (srow & 3)) * 8;
  const u16* pA[2];
  const u16* pB[2];
#pragma unroll
  for (int e = 0; e < 2; e++) {
    pA[e] = xt + (size_t)(r0 + e * 64 + wv * 16 + srow) * 256 + sg;
    pB[e] = w + (size_t)(j0 + e * 64 + wv * 16 + srow) * 256 + sg;
  }
  auto stage = [&](int buf, int k0) {
#pragma unroll
    for (int e = 0; e < 2; e++) {
      g2l16(pA[e] + k0, &sm.ab[buf][0][e * 64 + wv * 16][0]);
      g2l16(pB[e] + k0, &sm.ab[buf][1][e * 64 + wv * 16][0]);
    }
  };

  f32x4 acc[4][4] = {};
  stage(0, 0);
  __syncthreads();
  for (int ks = 0; ks < 8; ks++) {
    const int cur = ks & 1;
    if (ks < 7) stage(cur ^ 1, (ks + 1) * 32);  // async; drains at loop-end barrier
    bf16x8 a[4], b[4];
#pragma unroll
    for (int mt = 0; mt < 4; mt++)
      a[mt] = ldfrag(&sm.ab[cur][0][wm * 64 + mt * 16 + lr][(quad ^ (lr & 3)) * 8]);
#pragma unroll
    for (int nt = 0; nt < 4; nt++)
      b[nt] = ldfrag(&sm.ab[cur][1][wn * 64 + nt * 16 + lr][(quad ^ (lr & 3)) * 8]);
#pragma unroll
    for (int mt = 0; mt < 4; mt++)
#pragma unroll
      for (int nt = 0; nt < 4; nt++)
        acc[mt][nt] = __builtin_amdgcn_mfma_f32_16x16x32_bf16(a[mt], b[nt], acc[mt][nt], 0, 0, 0);
    __syncthreads();
  }

  float bj[4];
#pragma unroll
  for (int nt = 0; nt < 4; nt++) bj[nt] = bias[j0 + wn * 64 + nt * 16 + lr];
  __syncthreads();  // safety: union overwrite
  if (blockIdx.y < 4) {
    // q/k path: stage (acc+bias)*sc to LDS, then coalesced u16x8 stores
    const int part = blockIdx.y >> 1;  // 0=q, 1=k
    u16* outp = part ? kk_ : q;
    const float sc = part ? 1.0f : 0.18033688f;  // 0.125*log2(e), exp2-domain scores
#pragma unroll
    for (int nt = 0; nt < 4; nt++) {
      int lc = wn * 64 + nt * 16 + lr;
#pragma unroll
      for (int mt = 0; mt < 4; mt++)
#pragma unroll
        for (int rg = 0; rg < 4; rg++)
          sm.tile[wm * 64 + mt * 16 + quad * 4 + rg][lc] = f2bf((acc[mt][nt][rg] + bj[nt]) * sc);
    }
    __syncthreads();
    const int hb2 = (blockIdx.y & 1) * 2;  // head base within part
#pragma unroll
    for (int it = 0; it < 8; it++) {
      int seg = tid + it * 256;            // 2048 u16x8 segments
      int row = seg >> 4, cs = seg & 15;   // consecutive tids -> consecutive cols (coalesced)
      u16x8 o = *(const u16x8*)&sm.tile[row][cs * 8];
      int head = hb2 + (cs >> 3), d0 = (cs & 7) * 8;
      int rr = r0 + row, b_ = rr >> 12, s = rr & 4095;
      *(u16x8*)(outp + ((size_t)((b_ * 4 + head) * Ss + s) << 6) + d0) = o;
    }
  } else {
    // v path: acc tile -> LDS -> transposed+permuted vt write
    const int hb = (blockIdx.y - 4) * 2;  // head base (0 or 2)
#pragma unroll
    for (int nt = 0; nt < 4; nt++) {
      int lc = wn * 64 + nt * 16 + lr;
#pragma unroll
      for (int mt = 0; mt < 4; mt++)
#pragma unroll
        for (int rg = 0; rg < 4; rg++)
          sm.tile[wm * 64 + mt * 16 + quad * 4 + rg][lc] = f2bf(acc[mt][nt][rg] + bj[nt]);
    }
    __syncthreads();
    const int b2 = r0 >> 12, sbase = r0 & 4095;
#pragma unroll
    for (int it = 0; it < 8; it++) {
      int seg = tid + it * 256;        // 2048 u16x8 segments
      int sq = seg & 15, hd = seg >> 4;  // consecutive tids -> consecutive slots (coalesced)
      int c = sq >> 3, s8 = sq & 7;
      u16x8 o;
#pragma unroll
      for (int j = 0; j < 8; j++) {
        int slot = s8 * 8 + j;
        int sw = (((slot >> 5) & 1) << 5) | (((slot >> 2) & 1) << 4) |
                 (((slot >> 3) & 3) << 2) | (slot & 3);  // k_vt's w6 bijection
        o[j] = sm.tile[c * 64 + sw][hd];
      }
      int head = hb + (hd >> 6), d = hd & 63;
      *(u16x8*)(vt + ((size_t)((b2 * 4 + head) * 64 + d) << 12) + sbase + c * 64 + s8 * 8) = o;
    }
  }
}

// ---------------- kernel 2: flash attention, S^T form, exp2 no-max softmax ----------------
// r13 structure (70.0 us), MINUS all s_setprio: the setprio(1)/(0) pairs around each MFMA
// cluster likely acted as scheduler fences pinning the MFMA-burst/VALU-burst alternation
// (MfmaUtil 48 + VALUBusy 45 alternate, never overlap, though m114 proves the pipes CAN
// co-run). Removing them frees the compiler to interleave exp2/pack with independent MFMAs
// within the barrier-free sub-body.
__global__ __launch_bounds__(512, 4) void k_attn(const u16* __restrict__ Q, const u16* __restrict__ K,
                                                 const u16* __restrict__ VT, u16* __restrict__ AO,
                                                 u16* __restrict__ AOP, float* __restrict__ lpart,
                                                 int nsplit) {
  __shared__ union {
    struct { u16 Kl[2][2][64][64]; u16 Vl[2][2][64][64]; } s;  // 64 KB
    u16 W[8][32 * 72];                                         // epilogue: per-wave [32 q][72]
  } smem;
  const int tid = threadIdx.x;
  const int wv = tid >> 6, lane = tid & 63;
  const int lr = lane & 15, quad = lane >> 4;
  const int bh = blockIdx.y;
  const int b_ = bh >> 2, head = bh & 3;
  const int qbase = blockIdx.x * 256 + wv * 32;
  const int sp = blockIdx.z;
  const int nbig = 32 / nsplit, bg0 = sp * nbig;  // big chunks of 128 kv rows
  const u16* Qh = Q + (size_t)bh * Ss * HD;
  const u16* Kh = K + (size_t)bh * Ss * HD;
  const u16* Vh = VT + (size_t)bh * HD * Ss;  // [d][perm(s)]

  bf16x8 qb[2][2];
#pragma unroll
  for (int nt = 0; nt < 2; nt++)
#pragma unroll
    for (int ks = 0; ks < 2; ks++)
      qb[nt][ks] = ldfrag(Qh + (size_t)(qbase + nt * 16 + lr) * HD + ks * 32 + quad * 8);

  u16x8 ov;
#pragma unroll
  for (int j = 0; j < 8; j++) ov[j] = 0x3F80;
  const bf16x8 ones = __builtin_bit_cast(bf16x8, ov);

  f32x4 O[2][4] = {};
  f32x4 lacc[2] = {};

  // DMA staging: per sub-tile, 8 waves cover 64 rows (wave wv: rows wv*8..wv*8+7). Lane l
  // writes LDS granule (row = wv*8 + l>>3, slot = l&7); source granule = (l&7)^(l>>3).
  const int srow = wv * 8 + (lane >> 3);
  const int sseg = ((lane & 7) ^ (lane >> 3)) * 8;
  const u16* pK = Kh + ((size_t)(bg0 * 128 + srow) << 6) + sseg;
  const u16* pV = Vh + ((size_t)srow << 12) + bg0 * 128 + sseg;
  auto stage = [&](int buf) {
#pragma unroll
    for (int s = 0; s < 2; s++) {
      g2l16(pK + (s << 12), &smem.s.Kl[buf][s][wv * 8][0]);  // sub s: +64 rows * 64 cols
      g2l16(pV + s * 64, &smem.s.Vl[buf][s][wv * 8][0]);     // sub s: +64 slots
    }
    pK += 8192; pV += 128;  // next big chunk (128 kv rows / 128 slots)
  };

  stage(0);
  __syncthreads();

  for (int bc = 0; bc < nbig; bc++) {
    const int cur = bc & 1;
    if (bc + 1 < nbig) stage(cur ^ 1);  // async into other buffer; drains at loop-end barrier

#pragma unroll
    for (int sub = 0; sub < 2; sub++) {
      u32x4 pa[2][2];  // [kv-half][q-group]: packed bf16 P fragments (PV A-operands)
#pragma unroll
      for (int t = 0; t < 4; t++) {  // 16-row kv tiles within sub
        const int krow = t * 16 + lr;
        bf16x8 ka0 = ldfrag(&smem.s.Kl[cur][sub][krow][(quad ^ (lr & 7)) * 8]);
        bf16x8 ka1 = ldfrag(&smem.s.Kl[cur][sub][krow][((4 + quad) ^ (lr & 7)) * 8]);
        f32x4 St[2] = {};
#pragma unroll
        for (int nt = 0; nt < 2; nt++)
          St[nt] = __builtin_amdgcn_mfma_f32_16x16x32_bf16(ka0, qb[nt][0], St[nt], 0, 0, 0);
#pragma unroll
        for (int nt = 0; nt < 2; nt++)
          St[nt] = __builtin_amdgcn_mfma_f32_16x16x32_bf16(ka1, qb[nt][1], St[nt], 0, 0, 0);
        const int h = t >> 1, k2 = (t & 1) * 2;
#pragma unroll
        for (int nt = 0; nt < 2; nt++) {
          float p0 = __builtin_amdgcn_exp2f(St[nt][0]);
          float p1 = __builtin_amdgcn_exp2f(St[nt][1]);
          float p2 = __builtin_amdgcn_exp2f(St[nt][2]);
          float p3 = __builtin_amdgcn_exp2f(St[nt][3]);
          pa[h][nt][k2] = pack2bf_trunc(p0, p1);
          pa[h][nt][k2 + 1] = pack2bf_trunc(p2, p3);
        }
      }
#pragma unroll
      for (int h = 0; h < 2; h++) {
#pragma unroll
        for (int dt = 0; dt < 4; dt++) {
          bf16x8 vb = ldfrag(&smem.s.Vl[cur][sub][dt * 16 + lr][((h * 4 + quad) ^ (lr & 7)) * 8]);
#pragma unroll
          for (int mt = 0; mt < 2; mt++)
            O[mt][dt] = __builtin_amdgcn_mfma_f32_16x16x32_bf16(
                __builtin_bit_cast(bf16x8, pa[h][mt]), vb, O[mt][dt], 0, 0, 0);
        }
#pragma unroll
        for (int mt = 0; mt < 2; mt++)
          lacc[mt] = __builtin_amdgcn_mfma_f32_16x16x32_bf16(
              __builtin_bit_cast(bf16x8, pa[h][mt]), ones, lacc[mt], 0, 0, 0);
      }
    }
    __syncthreads();
  }

  // epilogue: normalize by this split's l; stage rows in per-wave LDS tile (Kl/Vl are dead
  // after the final barrier), then 128B-contiguous u16x8 global writes.
  u16* dst = (nsplit == 1) ? AO : (AOP + (size_t)sp * ELEMS);
  if (nsplit > 1 && lr == 0) {
    float* lp = lpart + (size_t)sp * (16 * Ss) + bh * Ss;
#pragma unroll
    for (int mt = 0; mt < 2; mt++)
#pragma unroll
      for (int rg = 0; rg < 4; rg++) lp[qbase + mt * 16 + quad * 4 + rg] = lacc[mt][rg];
  }
  u16* W = smem.W[wv];
#pragma unroll
  for (int mt = 0; mt < 2; mt++)
#pragma unroll
    for (int rg = 0; rg < 4; rg++) {
      float inv = 1.0f / lacc[mt][rg];
      int qq = mt * 16 + quad * 4 + rg;
#pragma unroll
      for (int dt = 0; dt < 4; dt++)
        W[qq * 72 + dt * 16 + lr] = f2bf(O[mt][dt][rg] * inv);
    }
  // each wave reads only its own W region; ds-op ordering within the wave is sufficient
#pragma unroll
  for (int e = 0; e < 4; e++) {
    int seg = lane + e * 64;
    int qq = seg >> 3, d0 = (seg & 7) * 8;
    u16x8 o = *(const u16x8*)&W[qq * 72 + d0];
    *(u16x8*)(dst + ((size_t)(b_ * Ss + qbase + qq) << 8) + head * 64 + d0) = o;
  }
}

// ---------------- kernel 3 (fused combine + oproj): y^T = w_o * combine(aop)^T + b_o ----------------
// 256(m = full C) x 64(n) tiles, 512 threads, grid 256 = 1 block/CU. Full-m tiles read AOP
// exactly once (-33.5 MB HBM, -half combine VALU vs the (256,2) split-m grid). Latency
// hidden by the double-buffered DMA loop (A via g2l16, one barrier per K-step). Epilogue:
// fp32 tile staged in LDS -> 256B-contiguous float4 y writes (4096 float4 segs = 8 iters).
__global__ __launch_bounds__(512) void k_oproj(const u16* __restrict__ wo, const u16* __restrict__ ao,
                                               const u16* __restrict__ AOP, const float* __restrict__ lpart,
                                               const float* __restrict__ bo, float* __restrict__ y, int nsplit) {
  __shared__ union {
    struct { u16 As[2][256][32]; u16 Bs[2][64][40]; } s;  // 32 KB + 10 KB
    float Ys[256][68];                                    // 69.6 KB epilogue
  } sm;
  const int tid = threadIdx.x;
  const int wv = tid >> 6, lane = tid & 63;
  const int wm = wv >> 1, wn = wv & 1;  // 4m x 2n wave layout, per-wave 64m x 32n
  const int lr = lane & 15, quad = lane >> 4;
  const int n0 = blockIdx.x * 64;

  // A staging: wave wv stages rows wv*32 + e*16 + (l>>2); source granule (l&3)^(row&3).
  const int arow = lane >> 2;
  const int ag = ((lane & 3) ^ (arow & 3)) * 8;
  const u16* pA[2];
#pragma unroll
  for (int e = 0; e < 2; e++)
    pA[e] = wo + (size_t)(wv * 32 + e * 16 + arow) * 256 + ag;
  auto stageA = [&](int buf, int k0) {
#pragma unroll
    for (int e = 0; e < 2; e++) g2l16(pA[e] + k0, &sm.s.As[buf][wv * 32 + e * 16][0]);
  };
  auto stageB = [&](int buf, int k0) {
    if (tid < 256) {  // 64 n-rows x 32 c-cols, l-weighted combine of normalized bf16 partials
      int row = tid >> 2, seg = tid & 3;
      int bs = n0 + row, cc = k0 + seg * 8;
      u16x8 t;
      if (nsplit == 1) {
        t = *(const u16x8*)(ao + ((size_t)bs << 8) + cc);
      } else {
        int b = bs >> 12, s = bs & 4095, head = cc >> 6;
        int li = (b * 4 + head) * Ss + s;
        float accv[8] = {0.f, 0.f, 0.f, 0.f, 0.f, 0.f, 0.f, 0.f};
        float lsum = 0.f;
        for (int spl = 0; spl < nsplit; spl++) {
          float l = lpart[(size_t)spl * (16 * Ss) + li];
          u16x8 a = *(const u16x8*)(AOP + (size_t)spl * ELEMS + ((size_t)bs << 8) + cc);
          lsum += l;
#pragma unroll
          for (int i = 0; i < 8; i++) accv[i] += l * bf2f(a[i]);
        }
        float inv = 1.0f / lsum;
#pragma unroll
        for (int i = 0; i < 8; i++) t[i] = f2bf(accv[i] * inv);
      }
      *(u16x8*)&sm.s.Bs[buf][row][seg * 8] = t;
    }
  };

  f32x4 acc[4][2] = {};
  stageA(0, 0);
  stageB(0, 0);
  __syncthreads();
  for (int ks = 0; ks < 8; ks++) {
    const int cur = ks & 1;
    if (ks < 7) {
      stageA(cur ^ 1, (ks + 1) * 32);  // async DMA; drains at loop-end barrier
      stageB(cur ^ 1, (ks + 1) * 32);  // VALU combine into the free buffer
    }
    bf16x8 a[4], b[2];
#pragma unroll
    for (int mt = 0; mt < 4; mt++)
      a[mt] = ldfrag(&sm.s.As[cur][wm * 64 + mt * 16 + lr][(quad ^ (lr & 3)) * 8]);
#pragma unroll
    for (int nt = 0; nt < 2; nt++) b[nt] = ldfrag(&sm.s.Bs[cur][wn * 32 + nt * 16 + lr][quad * 8]);
#pragma unroll
    for (int mt = 0; mt < 4; mt++)
#pragma unroll
      for (int nt = 0; nt < 2; nt++)
        acc[mt][nt] = __builtin_amdgcn_mfma_f32_16x16x32_bf16(a[mt], b[nt], acc[mt][nt], 0, 0, 0);
    __syncthreads();
  }
  // epilogue: stage fp32 output tile, then 256B-contiguous float4 y writes
#pragma unroll
  for (int mt = 0; mt < 4; mt++)
#pragma unroll
    for (int rg = 0; rg < 4; rg++) {
      int c = wm * 64 + mt * 16 + quad * 4 + rg;  // global c row (m covers all 256)
      float bc = bo[c];
#pragma unroll
      for (int nt = 0; nt < 2; nt++)
        sm.Ys[c][wn * 32 + nt * 16 + lr] = acc[mt][nt][rg] + bc;
    }
  __syncthreads();
  const int bglob = n0 >> 12, scol = n0 & 4095;
#pragma unroll
  for (int it = 0; it < 8; it++) {
    int idx = tid + it * 512;                 // 4096 float4 segments (256 c x 16)
    int row = idx >> 4, s4 = (idx & 15) * 4;  // consecutive tids -> consecutive cols
    float4 v = *(const float4*)&sm.Ys[row][s4];
    *(float4*)&y[((size_t)(bglob * Cc + row) << 12) + scol + s4] = v;
  }
}

extern "C" void kernel_launch(void* const* d_in, const int* in_sizes, int n_in,
                              void* d_out, int out_size, void* d_ws, size_t ws_size,
                              hipStream_t stream) {
  const float* x = (const float*)d_in[0];
  const float* w_qkv = (const float*)d_in[1];
  const float* b_qkv = (const float*)d_in[2];
  const float* w_o = (const float*)d_in[3];
  const float* b_o = (const float*)d_in[4];
  float* y = (float*)d_out;
  u16* ws = (u16*)d_ws;
  u16* xt = ws;                        // [0, E) — dead after k_qkv; reused as ao (nsplit==1)
  u16* q = ws + (size_t)ELEMS;
  u16* k = ws + (size_t)2 * ELEMS;
  u16* vt = ws + (size_t)3 * ELEMS;
  u16* ao = xt;
  u16* wqb = ws + (size_t)4 * ELEMS;   // 196608
  u16* wob = wqb + 196608;             // 65536
  const size_t Wu16 = (size_t)4 * ELEMS + 262144;
  // need(n) bytes = bf16 ws incl. n partial slabs, + n*16*Ss f32 for lpart
  auto need = [&](int n) { return (Wu16 + (size_t)n * ELEMS) * 2 + (size_t)n * 16 * Ss * 4; };
  const int nsplit = (ws_size >= need(2)) ? 2 : 1;
  u16* aop = ws + Wu16;                // nsplit*ELEMS u16 normalized partials
  float* lpart = (float*)(aop + (size_t)nsplit * ELEMS);

  k_transpose<<<dim3(64, 4, 4), 256, 0, stream>>>(x, xt, w_qkv, w_o, wqb, wob);
  k_qkv<<<dim3(128, 6), 256, 0, stream>>>(xt, wqb, b_qkv, q, k, vt);
  k_attn<<<dim3(16, 16, nsplit), 512, 0, stream>>>(q, k, vt, ao, aop, lpart, nsplit);
  k_oproj<<<256, 512, 0, stream>>>(wob, ao, aop, lpart, b_o, y, nsplit);
}